// Round 6
// baseline (839.211 us; speedup 1.0000x reference)
//
#include <hip/hip_runtime.h>

#define NN 100000
#define NE 1600000
#define DD 64

#define NPB 128                        // nodes per bucket
#define NBUCK ((NN + NPB - 1) / NPB)   // 782
#define CAP 3072                       // record capacity per bucket (mean 2046, sigma 45)
#define OVF_CAP 4096
#define CHUNK 16384                    // edges per partition block
#define NPART ((NE + CHUNK - 1) / CHUNK)  // 98

// ---------------- primary path: bucket partition + fused LDS aggregate ----------------

__global__ void __launch_bounds__(256) init_ws_kernel(int* __restrict__ gcur,
                                                      int* __restrict__ ovf_cnt) {
  int i = blockIdx.x * 256 + threadIdx.x;
  if (i < NBUCK) gcur[i] = i * CAP;
  if (i == 0) ovf_cnt[0] = 0;
}

// Pass A: partition edges into 782 buckets of 128 nodes (bucket = dst>>7).
// LDS hist -> one global atomicAdd per (block,bucket) -> contiguous-rank scatter
// of 4B packed records (src<<7)|(dst&127). ~84B bursts per bucket per block.
__global__ void __launch_bounds__(256) partition_kernel(
    const int* __restrict__ src, const int* __restrict__ dst,
    int* __restrict__ gcur, int* __restrict__ ovf_cnt, int* __restrict__ ovf,
    unsigned int* __restrict__ sorted) {
  __shared__ int hist[NBUCK];
  __shared__ int base[NBUCK];
  int tid = threadIdx.x;
  int chunk = blockIdx.x * CHUNK;

  for (int i = tid; i < NBUCK; i += 256) hist[i] = 0;
  __syncthreads();

  for (int i = 0; i < CHUNK / 256; ++i) {
    int e = chunk + i * 256 + tid;
    if (e < NE) atomicAdd(&hist[dst[e] >> 7], 1);
  }
  __syncthreads();

  for (int i = tid; i < NBUCK; i += 256)
    base[i] = atomicAdd(&gcur[i], hist[i]);
  __syncthreads();

  for (int i = 0; i < CHUNK / 256; ++i) {
    int e = chunk + i * 256 + tid;
    if (e < NE) {
      int s = src[e], d = dst[e];
      int bk = d >> 7;
      int pos = atomicAdd(&base[bk], 1);
      if (pos < (bk + 1) * CAP) {
        sorted[pos] = ((unsigned int)s << 7) | (unsigned int)(d & 127);
      } else {
        int oi = atomicAdd(ovf_cnt, 1);
        if (oi < OVF_CAP) { ovf[2 * oi] = s; ovf[2 * oi + 1] = d; }
      }
    }
  }
}

// Pass B: one block per bucket. acc[128][64] f32 in LDS; quarter-wave per
// record (2 in flight); gather feat[src] float4 -> ds_add_f32. Epilogue fuses
// (1+eps)*self and streams out rows coalesced.
__global__ void __launch_bounds__(256) bucket_agg_kernel(
    const float* __restrict__ feat, const float* __restrict__ eps,
    const int* __restrict__ gcur, const unsigned int* __restrict__ sorted,
    float* __restrict__ out) {
  __shared__ float acc[NPB * DD];  // 32 KB
  int tid = threadIdx.x;
  int bk = blockIdx.x;
  float4* acc4 = reinterpret_cast<float4*>(acc);
  const float4* f4 = reinterpret_cast<const float4*>(feat);

  for (int i = tid; i < NPB * DD / 4; i += 256)
    acc4[i] = make_float4(0.f, 0.f, 0.f, 0.f);
  __syncthreads();

  int base = bk * CAP;
  int cnt = gcur[bk] - base;
  if (cnt > CAP) cnt = CAP;
  int grp = tid >> 4, q = tid & 15;

  int r = grp * 2;
  for (; r + 2 <= cnt; r += 32) {
    unsigned int rec0 = sorted[base + r];
    unsigned int rec1 = sorted[base + r + 1];
    int s0 = rec0 >> 7, l0 = rec0 & 127;
    int s1 = rec1 >> 7, l1 = rec1 & 127;
    float4 v0 = f4[(size_t)s0 * 16 + q];
    float4 v1 = f4[(size_t)s1 * 16 + q];
    float* a0 = &acc[l0 * DD + q * 4];
    float* a1 = &acc[l1 * DD + q * 4];
    unsafeAtomicAdd(a0 + 0, v0.x); unsafeAtomicAdd(a0 + 1, v0.y);
    unsafeAtomicAdd(a0 + 2, v0.z); unsafeAtomicAdd(a0 + 3, v0.w);
    unsafeAtomicAdd(a1 + 0, v1.x); unsafeAtomicAdd(a1 + 1, v1.y);
    unsafeAtomicAdd(a1 + 2, v1.z); unsafeAtomicAdd(a1 + 3, v1.w);
  }
  if (r < cnt) {
    unsigned int rec = sorted[base + r];
    int s = rec >> 7, l = rec & 127;
    float4 v = f4[(size_t)s * 16 + q];
    float* a = &acc[l * DD + q * 4];
    unsafeAtomicAdd(a + 0, v.x); unsafeAtomicAdd(a + 1, v.y);
    unsafeAtomicAdd(a + 2, v.z); unsafeAtomicAdd(a + 3, v.w);
  }
  __syncthreads();

  float e = 1.0f + eps[0];
  int node0 = bk * NPB;
  for (int i = tid; i < NPB * 16; i += 256) {
    int ln = i >> 4, qq = i & 15;
    int row = node0 + ln;
    if (row < NN) {
      float4 a = acc4[ln * 16 + qq];
      float4 sf = f4[(size_t)row * 16 + qq];
      reinterpret_cast<float4*>(out)[(size_t)row * 16 + qq] =
          make_float4(e * sf.x + a.x, e * sf.y + a.y, e * sf.z + a.z, e * sf.w + a.w);
    }
  }
}

// overflow fixup (expected 0 entries): out[dst] += feat[src] via global f32 atomics
__global__ void __launch_bounds__(256) ovf_fix_kernel(
    const float* __restrict__ feat, const int* __restrict__ ovf_cnt,
    const int* __restrict__ ovf, float* __restrict__ out) {
  int n = ovf_cnt[0];
  if (n > OVF_CAP) n = OVF_CAP;
  int t = blockIdx.x * blockDim.x + threadIdx.x;
  for (int i = t; i < n * 16; i += gridDim.x * blockDim.x) {
    int idx = i >> 4, q = i & 15;
    int s = ovf[2 * idx], d = ovf[2 * idx + 1];
    float4 v = reinterpret_cast<const float4*>(feat)[(size_t)s * 16 + q];
    float* op = out + (size_t)d * DD + q * 4;
    unsafeAtomicAdd(op + 0, v.x); unsafeAtomicAdd(op + 1, v.y);
    unsafeAtomicAdd(op + 2, v.z); unsafeAtomicAdd(op + 3, v.w);
  }
}

// in-place row GEMM v3: thread = output column (lane), W column in VGPRs,
// rst broadcast via v_readlane -> fma. Spill-proof, no LDS.
__global__ void __launch_bounds__(256) row_gemm3_kernel(float* __restrict__ out,
                                                        const float* __restrict__ W,
                                                        const float* __restrict__ b) {
  int lane = threadIdx.x & 63;
  int wid  = threadIdx.x >> 6;
  int g = blockIdx.x * 4 + wid;
  if (g >= NN / 16) return;  // wave-uniform guard (6250 full waves)
  int row0 = g * 16;

  float w[64];
#pragma unroll
  for (int k = 0; k < 64; ++k) w[k] = W[k * DD + lane];
  float bv = b[lane];

#pragma unroll
  for (int batch = 0; batch < 2; ++batch) {
    int rbase = row0 + batch * 8;
    float rst[8], acc[8];
#pragma unroll
    for (int r = 0; r < 8; ++r) rst[r] = out[(size_t)(rbase + r) * DD + lane];
#pragma unroll
    for (int r = 0; r < 8; ++r) acc[r] = bv;
#pragma unroll
    for (int k = 0; k < 64; ++k) {
#pragma unroll
      for (int r = 0; r < 8; ++r) {
        float s = __uint_as_float(__builtin_amdgcn_readlane(__float_as_uint(rst[r]), k));
        acc[r] = fmaf(s, w[k], acc[r]);
      }
    }
#pragma unroll
    for (int r = 0; r < 8; ++r) out[(size_t)(rbase + r) * DD + lane] = acc[r];
  }
}

// ---------------- fallback path B: round-4 CSR pipeline ----------------

constexpr int NB_SCAN = (NN + 1023) / 1024;

__global__ void __launch_bounds__(256) zero_kernel(int* __restrict__ p, int n) {
  int i = blockIdx.x * blockDim.x + threadIdx.x;
  if (i < n) p[i] = 0;
}

__global__ void __launch_bounds__(256) hist_kernel(const int* __restrict__ dst,
                                                   int* __restrict__ count) {
  int e = blockIdx.x * blockDim.x + threadIdx.x;
  atomicAdd(&count[dst[e]], 1);
}

__global__ void __launch_bounds__(1024) scan1_kernel(const int* __restrict__ count,
                                                     int* __restrict__ offsets,
                                                     int* __restrict__ bsums) {
  __shared__ int tmp[1024];
  int tid = threadIdx.x;
  int gid = blockIdx.x * 1024 + tid;
  int v = (gid < NN) ? count[gid] : 0;
  tmp[tid] = v;
  __syncthreads();
  for (int off = 1; off < 1024; off <<= 1) {
    int t = (tid >= off) ? tmp[tid - off] : 0;
    __syncthreads();
    tmp[tid] += t;
    __syncthreads();
  }
  if (gid < NN) offsets[gid] = tmp[tid] - v;
  if (tid == 1023) bsums[blockIdx.x] = tmp[1023];
}

__global__ void __launch_bounds__(128) scan2_kernel(int* __restrict__ bsums) {
  __shared__ int tmp[128];
  int tid = threadIdx.x;
  int v = (tid < NB_SCAN) ? bsums[tid] : 0;
  tmp[tid] = v;
  __syncthreads();
  for (int off = 1; off < 128; off <<= 1) {
    int t = (tid >= off) ? tmp[tid - off] : 0;
    __syncthreads();
    tmp[tid] += t;
    __syncthreads();
  }
  if (tid < NB_SCAN) bsums[tid] = tmp[tid] - v;
}

__global__ void __launch_bounds__(256) scan3_kernel(int* __restrict__ offsets,
                                                    const int* __restrict__ bsums,
                                                    int* __restrict__ cursor) {
  int gid = blockIdx.x * blockDim.x + threadIdx.x;
  if (gid < NN) {
    int o = offsets[gid] + bsums[gid >> 10];
    offsets[gid] = o;
    cursor[gid] = o;
  } else if (gid == NN) {
    offsets[NN] = NE;
  }
}

__global__ void __launch_bounds__(256) place_kernel(const int* __restrict__ src,
                                                    const int* __restrict__ dst,
                                                    int* __restrict__ cursor,
                                                    int* __restrict__ sorted) {
  int e = blockIdx.x * blockDim.x + threadIdx.x;
  int p = atomicAdd(&cursor[dst[e]], 1);
  sorted[p] = src[e];
}

__global__ void __launch_bounds__(256) pull4_kernel(const float* __restrict__ feat,
                                                    const float* __restrict__ eps,
                                                    const int* __restrict__ offsets,
                                                    const int* __restrict__ sorted,
                                                    float* __restrict__ out) {
  int t = blockIdx.x * blockDim.x + threadIdx.x;
  int node = t >> 4;
  int q = t & 15;
  const float4* f4 = reinterpret_cast<const float4*>(feat);

  int start = offsets[node];
  int end   = offsets[node + 1];
  float e = 1.0f + eps[0];
  float4 self = f4[(size_t)node * 16 + q];
  float ax = e * self.x, ay = e * self.y, az = e * self.z, aw = e * self.w;

  int k = start;
  for (; k + 4 <= end; k += 4) {
    int s0 = sorted[k + 0], s1 = sorted[k + 1], s2 = sorted[k + 2], s3 = sorted[k + 3];
    float4 v0 = f4[(size_t)s0 * 16 + q];
    float4 v1 = f4[(size_t)s1 * 16 + q];
    float4 v2 = f4[(size_t)s2 * 16 + q];
    float4 v3 = f4[(size_t)s3 * 16 + q];
    ax += (v0.x + v1.x) + (v2.x + v3.x);
    ay += (v0.y + v1.y) + (v2.y + v3.y);
    az += (v0.z + v1.z) + (v2.z + v3.z);
    aw += (v0.w + v1.w) + (v2.w + v3.w);
  }
  for (; k < end; ++k) {
    int s = sorted[k];
    float4 v = f4[(size_t)s * 16 + q];
    ax += v.x; ay += v.y; az += v.z; aw += v.w;
  }

  reinterpret_cast<float4*>(out)[(size_t)node * 16 + q] = make_float4(ax, ay, az, aw);
}

// ---------------- fallback path C: atomic scatter ----------------

__global__ void __launch_bounds__(256) init_out_kernel(const float* __restrict__ feat,
                                                       const float* __restrict__ eps,
                                                       float* __restrict__ out) {
  int i = blockIdx.x * blockDim.x + threadIdx.x;
  float e = 1.0f + eps[0];
  float4 f = reinterpret_cast<const float4*>(feat)[i];
  reinterpret_cast<float4*>(out)[i] = make_float4(e * f.x, e * f.y, e * f.z, e * f.w);
}

__global__ void __launch_bounds__(256) scatter_edges_kernel(const float* __restrict__ feat,
                                                            const int* __restrict__ src,
                                                            const int* __restrict__ dst,
                                                            float* __restrict__ out) {
  int t = blockIdx.x * blockDim.x + threadIdx.x;
  int e = t >> 4;
  int q = t & 15;
  int s = src[e];
  int d = dst[e];
  float4 v = reinterpret_cast<const float4*>(feat)[s * 16 + q];
  float* op = out + d * DD + q * 4;
  atomicAdd(op + 0, v.x);
  atomicAdd(op + 1, v.y);
  atomicAdd(op + 2, v.z);
  atomicAdd(op + 3, v.w);
}

// ---------------- launch ----------------

extern "C" void kernel_launch(void* const* d_in, const int* in_sizes, int n_in,
                              void* d_out, int out_size, void* d_ws, size_t ws_size,
                              hipStream_t stream) {
  const float* feat = (const float*)d_in[0];
  const int* src    = (const int*)d_in[1];
  const int* dst    = (const int*)d_in[2];
  const float* eps  = (const float*)d_in[3];
  const float* W    = (const float*)d_in[4];
  const float* b    = (const float*)d_in[5];
  float* out        = (float*)d_out;

  const int gemm_grid = (NN / 16 + 3) / 4;  // 6250 waves / 4 per block

  // primary ws layout (ints): gcur[NBUCK] | ovf_cnt pad 2 | ovf[2*OVF_CAP] | sorted[NBUCK*CAP]
  const size_t needA = ((size_t)NBUCK + 2 + 2 * OVF_CAP + (size_t)NBUCK * CAP) * sizeof(int);
  // fallback B layout (ints): count[NN] | offsets[NN+1 pad 8] | cursor[NN] | bsums[128] | sorted[NE]
  const size_t needB = ((size_t)3 * NN + 136 + NE) * sizeof(int);

  if (ws_size >= needA) {
    int* wsI = (int*)d_ws;
    int* gcur    = wsI;
    int* ovf_cnt = wsI + NBUCK;
    int* ovf     = wsI + NBUCK + 2;
    unsigned int* sorted = (unsigned int*)(wsI + NBUCK + 2 + 2 * OVF_CAP);

    init_ws_kernel<<<(NBUCK + 256) / 256, 256, 0, stream>>>(gcur, ovf_cnt);
    partition_kernel<<<NPART, 256, 0, stream>>>(src, dst, gcur, ovf_cnt, ovf, sorted);
    bucket_agg_kernel<<<NBUCK, 256, 0, stream>>>(feat, eps, gcur, sorted, out);
    ovf_fix_kernel<<<8, 256, 0, stream>>>(feat, ovf_cnt, ovf, out);
    row_gemm3_kernel<<<gemm_grid, 256, 0, stream>>>(out, W, b);
  } else if (ws_size >= needB) {
    int* wsI     = (int*)d_ws;
    int* count   = wsI;
    int* offsets = wsI + NN;
    int* cursor  = wsI + 2 * NN + 8;
    int* bsums   = wsI + 3 * NN + 8;
    int* sortedB = wsI + 3 * NN + 136;

    zero_kernel<<<(NN + 255) / 256, 256, 0, stream>>>(count, NN);
    hist_kernel<<<NE / 256, 256, 0, stream>>>(dst, count);
    scan1_kernel<<<NB_SCAN, 1024, 0, stream>>>(count, offsets, bsums);
    scan2_kernel<<<1, 128, 0, stream>>>(bsums);
    scan3_kernel<<<(NN + 1 + 255) / 256, 256, 0, stream>>>(offsets, bsums, cursor);
    place_kernel<<<NE / 256, 256, 0, stream>>>(src, dst, cursor, sortedB);
    pull4_kernel<<<(NN * 16) / 256, 256, 0, stream>>>(feat, eps, offsets, sortedB, out);
    row_gemm3_kernel<<<gemm_grid, 256, 0, stream>>>(out, W, b);
  } else {
    init_out_kernel<<<(NN * DD / 4) / 256, 256, 0, stream>>>(feat, eps, out);
    scatter_edges_kernel<<<(NE * 16) / 256, 256, 0, stream>>>(feat, src, dst, out);
    row_gemm3_kernel<<<gemm_grid, 256, 0, stream>>>(out, W, b);
  }
}

// Round 7
// 207.131 us; speedup vs baseline: 4.0516x; 4.0516x over previous
//
#include <hip/hip_runtime.h>

#define NN 100000
#define NE 1600000
#define DD 64

#define NPB 128                        // nodes per bucket
#define NBUCK ((NN + NPB - 1) / NPB)   // 782
#define CAP 3072                       // record capacity per bucket (mean 2046, sigma 45)
#define OVF_CAP 4096
#define CHUNK 4096                     // edges per partition block
#define NPART ((NE + CHUNK - 1) / CHUNK)  // 391

// ---------------- primary path: bucket partition + in-LDS CSR + pull ----------------

__global__ void __launch_bounds__(256) init_ws_kernel(int* __restrict__ gcur,
                                                      int* __restrict__ ovf_cnt) {
  int i = blockIdx.x * 256 + threadIdx.x;
  if (i < NBUCK) gcur[i] = i * CAP;
  if (i == 0) ovf_cnt[0] = 0;
}

// Pass A: partition edges into 782 buckets of 128 nodes (bucket = dst>>7).
// LDS hist -> one global atomicAdd per (block,bucket) -> contiguous-rank scatter
// of 4B packed records (src<<7)|(dst&127).
__global__ void __launch_bounds__(256) partition_kernel(
    const int* __restrict__ src, const int* __restrict__ dst,
    int* __restrict__ gcur, int* __restrict__ ovf_cnt, int* __restrict__ ovf,
    unsigned int* __restrict__ sorted) {
  __shared__ int hist[NBUCK];
  __shared__ int base[NBUCK];
  int tid = threadIdx.x;
  int chunk = blockIdx.x * CHUNK;

  for (int i = tid; i < NBUCK; i += 256) hist[i] = 0;
  __syncthreads();

#pragma unroll
  for (int i = 0; i < CHUNK / 256; ++i) {
    int e = chunk + i * 256 + tid;
    if (e < NE) atomicAdd(&hist[dst[e] >> 7], 1);
  }
  __syncthreads();

  for (int i = tid; i < NBUCK; i += 256)
    base[i] = atomicAdd(&gcur[i], hist[i]);
  __syncthreads();

#pragma unroll
  for (int i = 0; i < CHUNK / 256; ++i) {
    int e = chunk + i * 256 + tid;
    if (e < NE) {
      int s = src[e], d = dst[e];
      int bk = d >> 7;
      int pos = atomicAdd(&base[bk], 1);
      if (pos < (bk + 1) * CAP) {
        sorted[pos] = ((unsigned int)s << 7) | (unsigned int)(d & 127);
      } else {
        int oi = atomicAdd(ovf_cnt, 1);
        if (oi < OVF_CAP) { ovf[2 * oi] = s; ovf[2 * oi + 1] = d; }
      }
    }
  }
}

// Pass B v2: one block per bucket. Build a LOCAL CSR in LDS (int hist + scan +
// scatter of src ids), then pull4-style per-node gather: quarter-wave per node,
// 4 independent float4 gathers in flight, register accumulation, fused
// (1+eps)*self, coalesced store. No f32 LDS atomics anywhere.
__global__ void __launch_bounds__(256) bucket_agg2_kernel(
    const float* __restrict__ feat, const float* __restrict__ eps,
    const int* __restrict__ gcur, const unsigned int* __restrict__ sorted,
    float* __restrict__ out) {
  __shared__ int lhist[NPB];
  __shared__ int loffs[NPB];   // inclusive scan of lhist
  __shared__ int lcur[NPB];
  __shared__ int srcs[CAP];    // 12 KB: src ids grouped by local node
  int tid = threadIdx.x;
  int bk = blockIdx.x;
  int base = bk * CAP;
  int cnt = gcur[bk] - base;
  if (cnt > CAP) cnt = CAP;
  const float4* f4 = reinterpret_cast<const float4*>(feat);

  if (tid < NPB) lhist[tid] = 0;
  __syncthreads();

  // local histogram over 128 node slots (int LDS atomics, cheap)
  for (int i = tid; i < cnt; i += 256)
    atomicAdd(&lhist[sorted[base + i] & 127], 1);
  __syncthreads();

  // inclusive Hillis-Steele scan of 128 counters
  if (tid < NPB) loffs[tid] = lhist[tid];
  __syncthreads();
  for (int off = 1; off < NPB; off <<= 1) {
    int t = 0;
    if (tid < NPB && tid >= off) t = loffs[tid - off];
    __syncthreads();
    if (tid < NPB) loffs[tid] += t;
    __syncthreads();
  }
  if (tid < NPB) lcur[tid] = loffs[tid] - lhist[tid];  // exclusive start
  __syncthreads();

  // scatter src ids into per-node-grouped LDS order
  for (int i = tid; i < cnt; i += 256) {
    unsigned int rec = sorted[base + i];
    int pos = atomicAdd(&lcur[rec & 127], 1);
    srcs[pos] = (int)(rec >> 7);
  }
  __syncthreads();

  // pull: quarter-wave per local node, 8 nodes per group, 4-deep gather MLP
  float ec = 1.0f + eps[0];
  int grp = tid >> 4, q = tid & 15;
  int node0 = bk * NPB;
  for (int ln = grp; ln < NPB; ln += 16) {
    int row = node0 + ln;
    if (row >= NN) break;  // rows monotonic per group; only last bucket partial
    int s = loffs[ln] - lhist[ln];
    int e2 = loffs[ln];
    float4 sf = f4[(size_t)row * 16 + q];
    float ax = ec * sf.x, ay = ec * sf.y, az = ec * sf.z, aw = ec * sf.w;
    int k = s;
    for (; k + 4 <= e2; k += 4) {
      int s0 = srcs[k + 0], s1 = srcs[k + 1], s2 = srcs[k + 2], s3 = srcs[k + 3];
      float4 v0 = f4[(size_t)s0 * 16 + q];
      float4 v1 = f4[(size_t)s1 * 16 + q];
      float4 v2 = f4[(size_t)s2 * 16 + q];
      float4 v3 = f4[(size_t)s3 * 16 + q];
      ax += (v0.x + v1.x) + (v2.x + v3.x);
      ay += (v0.y + v1.y) + (v2.y + v3.y);
      az += (v0.z + v1.z) + (v2.z + v3.z);
      aw += (v0.w + v1.w) + (v2.w + v3.w);
    }
    for (; k < e2; ++k) {
      int s4 = srcs[k];
      float4 v = f4[(size_t)s4 * 16 + q];
      ax += v.x; ay += v.y; az += v.z; aw += v.w;
    }
    reinterpret_cast<float4*>(out)[(size_t)row * 16 + q] =
        make_float4(ax, ay, az, aw);
  }
}

// overflow fixup (expected 0 entries): out[dst] += feat[src] via global f32 atomics
__global__ void __launch_bounds__(256) ovf_fix_kernel(
    const float* __restrict__ feat, const int* __restrict__ ovf_cnt,
    const int* __restrict__ ovf, float* __restrict__ out) {
  int n = ovf_cnt[0];
  if (n > OVF_CAP) n = OVF_CAP;
  int t = blockIdx.x * blockDim.x + threadIdx.x;
  for (int i = t; i < n * 16; i += gridDim.x * blockDim.x) {
    int idx = i >> 4, q = i & 15;
    int s = ovf[2 * idx], d = ovf[2 * idx + 1];
    float4 v = reinterpret_cast<const float4*>(feat)[(size_t)s * 16 + q];
    float* op = out + (size_t)d * DD + q * 4;
    unsafeAtomicAdd(op + 0, v.x); unsafeAtomicAdd(op + 1, v.y);
    unsafeAtomicAdd(op + 2, v.z); unsafeAtomicAdd(op + 3, v.w);
  }
}

// in-place row GEMM v3: thread = output column (lane), W column in VGPRs,
// rst broadcast via v_readlane -> fma. Spill-proof, no LDS.
__global__ void __launch_bounds__(256) row_gemm3_kernel(float* __restrict__ out,
                                                        const float* __restrict__ W,
                                                        const float* __restrict__ b) {
  int lane = threadIdx.x & 63;
  int wid  = threadIdx.x >> 6;
  int g = blockIdx.x * 4 + wid;
  if (g >= NN / 16) return;  // wave-uniform guard (6250 full waves)
  int row0 = g * 16;

  float w[64];
#pragma unroll
  for (int k = 0; k < 64; ++k) w[k] = W[k * DD + lane];
  float bv = b[lane];

#pragma unroll
  for (int batch = 0; batch < 2; ++batch) {
    int rbase = row0 + batch * 8;
    float rst[8], acc[8];
#pragma unroll
    for (int r = 0; r < 8; ++r) rst[r] = out[(size_t)(rbase + r) * DD + lane];
#pragma unroll
    for (int r = 0; r < 8; ++r) acc[r] = bv;
#pragma unroll
    for (int k = 0; k < 64; ++k) {
#pragma unroll
      for (int r = 0; r < 8; ++r) {
        float s = __uint_as_float(__builtin_amdgcn_readlane(__float_as_uint(rst[r]), k));
        acc[r] = fmaf(s, w[k], acc[r]);
      }
    }
#pragma unroll
    for (int r = 0; r < 8; ++r) out[(size_t)(rbase + r) * DD + lane] = acc[r];
  }
}

// ---------------- fallback path B: round-4 CSR pipeline ----------------

constexpr int NB_SCAN = (NN + 1023) / 1024;

__global__ void __launch_bounds__(256) zero_kernel(int* __restrict__ p, int n) {
  int i = blockIdx.x * blockDim.x + threadIdx.x;
  if (i < n) p[i] = 0;
}

__global__ void __launch_bounds__(256) hist_kernel(const int* __restrict__ dst,
                                                   int* __restrict__ count) {
  int e = blockIdx.x * blockDim.x + threadIdx.x;
  atomicAdd(&count[dst[e]], 1);
}

__global__ void __launch_bounds__(1024) scan1_kernel(const int* __restrict__ count,
                                                     int* __restrict__ offsets,
                                                     int* __restrict__ bsums) {
  __shared__ int tmp[1024];
  int tid = threadIdx.x;
  int gid = blockIdx.x * 1024 + tid;
  int v = (gid < NN) ? count[gid] : 0;
  tmp[tid] = v;
  __syncthreads();
  for (int off = 1; off < 1024; off <<= 1) {
    int t = (tid >= off) ? tmp[tid - off] : 0;
    __syncthreads();
    tmp[tid] += t;
    __syncthreads();
  }
  if (gid < NN) offsets[gid] = tmp[tid] - v;
  if (tid == 1023) bsums[blockIdx.x] = tmp[1023];
}

__global__ void __launch_bounds__(128) scan2_kernel(int* __restrict__ bsums) {
  __shared__ int tmp[128];
  int tid = threadIdx.x;
  int v = (tid < NB_SCAN) ? bsums[tid] : 0;
  tmp[tid] = v;
  __syncthreads();
  for (int off = 1; off < 128; off <<= 1) {
    int t = (tid >= off) ? tmp[tid - off] : 0;
    __syncthreads();
    tmp[tid] += t;
    __syncthreads();
  }
  if (tid < NB_SCAN) bsums[tid] = tmp[tid] - v;
}

__global__ void __launch_bounds__(256) scan3_kernel(int* __restrict__ offsets,
                                                    const int* __restrict__ bsums,
                                                    int* __restrict__ cursor) {
  int gid = blockIdx.x * blockDim.x + threadIdx.x;
  if (gid < NN) {
    int o = offsets[gid] + bsums[gid >> 10];
    offsets[gid] = o;
    cursor[gid] = o;
  } else if (gid == NN) {
    offsets[NN] = NE;
  }
}

__global__ void __launch_bounds__(256) place_kernel(const int* __restrict__ src,
                                                    const int* __restrict__ dst,
                                                    int* __restrict__ cursor,
                                                    int* __restrict__ sorted) {
  int e = blockIdx.x * blockDim.x + threadIdx.x;
  int p = atomicAdd(&cursor[dst[e]], 1);
  sorted[p] = src[e];
}

__global__ void __launch_bounds__(256) pull4_kernel(const float* __restrict__ feat,
                                                    const float* __restrict__ eps,
                                                    const int* __restrict__ offsets,
                                                    const int* __restrict__ sorted,
                                                    float* __restrict__ out) {
  int t = blockIdx.x * blockDim.x + threadIdx.x;
  int node = t >> 4;
  int q = t & 15;
  const float4* f4 = reinterpret_cast<const float4*>(feat);

  int start = offsets[node];
  int end   = offsets[node + 1];
  float e = 1.0f + eps[0];
  float4 self = f4[(size_t)node * 16 + q];
  float ax = e * self.x, ay = e * self.y, az = e * self.z, aw = e * self.w;

  int k = start;
  for (; k + 4 <= end; k += 4) {
    int s0 = sorted[k + 0], s1 = sorted[k + 1], s2 = sorted[k + 2], s3 = sorted[k + 3];
    float4 v0 = f4[(size_t)s0 * 16 + q];
    float4 v1 = f4[(size_t)s1 * 16 + q];
    float4 v2 = f4[(size_t)s2 * 16 + q];
    float4 v3 = f4[(size_t)s3 * 16 + q];
    ax += (v0.x + v1.x) + (v2.x + v3.x);
    ay += (v0.y + v1.y) + (v2.y + v3.y);
    az += (v0.z + v1.z) + (v2.z + v3.z);
    aw += (v0.w + v1.w) + (v2.w + v3.w);
  }
  for (; k < end; ++k) {
    int s = sorted[k];
    float4 v = f4[(size_t)s * 16 + q];
    ax += v.x; ay += v.y; az += v.z; aw += v.w;
  }

  reinterpret_cast<float4*>(out)[(size_t)node * 16 + q] = make_float4(ax, ay, az, aw);
}

// ---------------- fallback path C: atomic scatter ----------------

__global__ void __launch_bounds__(256) init_out_kernel(const float* __restrict__ feat,
                                                       const float* __restrict__ eps,
                                                       float* __restrict__ out) {
  int i = blockIdx.x * blockDim.x + threadIdx.x;
  float e = 1.0f + eps[0];
  float4 f = reinterpret_cast<const float4*>(feat)[i];
  reinterpret_cast<float4*>(out)[i] = make_float4(e * f.x, e * f.y, e * f.z, e * f.w);
}

__global__ void __launch_bounds__(256) scatter_edges_kernel(const float* __restrict__ feat,
                                                            const int* __restrict__ src,
                                                            const int* __restrict__ dst,
                                                            float* __restrict__ out) {
  int t = blockIdx.x * blockDim.x + threadIdx.x;
  int e = t >> 4;
  int q = t & 15;
  int s = src[e];
  int d = dst[e];
  float4 v = reinterpret_cast<const float4*>(feat)[s * 16 + q];
  float* op = out + d * DD + q * 4;
  atomicAdd(op + 0, v.x);
  atomicAdd(op + 1, v.y);
  atomicAdd(op + 2, v.z);
  atomicAdd(op + 3, v.w);
}

// ---------------- launch ----------------

extern "C" void kernel_launch(void* const* d_in, const int* in_sizes, int n_in,
                              void* d_out, int out_size, void* d_ws, size_t ws_size,
                              hipStream_t stream) {
  const float* feat = (const float*)d_in[0];
  const int* src    = (const int*)d_in[1];
  const int* dst    = (const int*)d_in[2];
  const float* eps  = (const float*)d_in[3];
  const float* W    = (const float*)d_in[4];
  const float* b    = (const float*)d_in[5];
  float* out        = (float*)d_out;

  const int gemm_grid = (NN / 16 + 3) / 4;  // 6250 waves / 4 per block

  // primary ws layout (ints): gcur[NBUCK] | ovf_cnt pad 2 | ovf[2*OVF_CAP] | sorted[NBUCK*CAP]
  const size_t needA = ((size_t)NBUCK + 2 + 2 * OVF_CAP + (size_t)NBUCK * CAP) * sizeof(int);
  // fallback B layout (ints): count[NN] | offsets[NN+1 pad 8] | cursor[NN] | bsums[128] | sorted[NE]
  const size_t needB = ((size_t)3 * NN + 136 + NE) * sizeof(int);

  if (ws_size >= needA) {
    int* wsI = (int*)d_ws;
    int* gcur    = wsI;
    int* ovf_cnt = wsI + NBUCK;
    int* ovf     = wsI + NBUCK + 2;
    unsigned int* sorted = (unsigned int*)(wsI + NBUCK + 2 + 2 * OVF_CAP);

    init_ws_kernel<<<(NBUCK + 256) / 256, 256, 0, stream>>>(gcur, ovf_cnt);
    partition_kernel<<<NPART, 256, 0, stream>>>(src, dst, gcur, ovf_cnt, ovf, sorted);
    bucket_agg2_kernel<<<NBUCK, 256, 0, stream>>>(feat, eps, gcur, sorted, out);
    ovf_fix_kernel<<<8, 256, 0, stream>>>(feat, ovf_cnt, ovf, out);
    row_gemm3_kernel<<<gemm_grid, 256, 0, stream>>>(out, W, b);
  } else if (ws_size >= needB) {
    int* wsI     = (int*)d_ws;
    int* count   = wsI;
    int* offsets = wsI + NN;
    int* cursor  = wsI + 2 * NN + 8;
    int* bsums   = wsI + 3 * NN + 8;
    int* sortedB = wsI + 3 * NN + 136;

    zero_kernel<<<(NN + 255) / 256, 256, 0, stream>>>(count, NN);
    hist_kernel<<<NE / 256, 256, 0, stream>>>(dst, count);
    scan1_kernel<<<NB_SCAN, 1024, 0, stream>>>(count, offsets, bsums);
    scan2_kernel<<<1, 128, 0, stream>>>(bsums);
    scan3_kernel<<<(NN + 1 + 255) / 256, 256, 0, stream>>>(offsets, bsums, cursor);
    place_kernel<<<NE / 256, 256, 0, stream>>>(src, dst, cursor, sortedB);
    pull4_kernel<<<(NN * 16) / 256, 256, 0, stream>>>(feat, eps, offsets, sortedB, out);
    row_gemm3_kernel<<<gemm_grid, 256, 0, stream>>>(out, W, b);
  } else {
    init_out_kernel<<<(NN * DD / 4) / 256, 256, 0, stream>>>(feat, eps, out);
    scatter_edges_kernel<<<(NE * 16) / 256, 256, 0, stream>>>(feat, src, dst, out);
    row_gemm3_kernel<<<gemm_grid, 256, 0, stream>>>(out, W, b);
  }
}